// Round 8
// baseline (263.396 us; speedup 1.0000x reference)
//
#include <hip/hip_runtime.h>
#include <math.h>

// Problem constants
#define NB   2
#define SEQ  2048
#define CH   768
#define NH   12
#define HD   64
#define F3   2304
#define LSMAX 4.605170185988092f
#define LOG2E 1.4426950408889634f

typedef _Float16 f16;
typedef __attribute__((ext_vector_type(8))) _Float16 f16x8;
typedef __attribute__((ext_vector_type(4))) _Float16 f16x4;
typedef __attribute__((ext_vector_type(2))) _Float16 f16x2;
typedef __attribute__((ext_vector_type(4))) float f32x4;

// f16 workspace layout (units: f16 elements)
#define QSZ   3145728                 // per Q/K/V tensor
#define OATT  (3 * QSZ)               // attn out [N,L,C] f16 (3145728)
#define XHOFF 12582912                // x -> f16 (3145728)
#define W1OFF 15728640                // in_proj_w -> f16 (1769472)
#define W2OFF 17498112                // out_proj_w -> f16 (589824)
#define FLAGO 18087936                // int flag: mask nonzero

// LDS pitches
#define VP   136   // attn Vt tile (128 keys): 272B rows, 16B-aligned b128
#define PPIT 76    // attn P tile: 152B rows, b64 frag reads, conflict-free
#define GP   40    // GEMM tiles: 80B rows, 16B-aligned b128

// ---------------------------------------------------------------------------
// fp32 -> f16 convert of X, W1, W2; mask is scanned for nonzero only.
// ---------------------------------------------------------------------------
__global__ __launch_bounds__(256) void cvt_f16(const float* __restrict__ X,
                                               const float* __restrict__ W1,
                                               const float* __restrict__ W2,
                                               const float* __restrict__ M,
                                               f16* __restrict__ Xh,
                                               f16* __restrict__ W1h,
                                               f16* __restrict__ W2h,
                                               int* __restrict__ flag)
{
    int tid = blockIdx.x * 256 + threadIdx.x;
    if (blockIdx.y == 3) {   // mask: flag-only scan
        if (tid < 1048576) {
            float4 v = ((const float4*)M)[tid];
            bool nz = (v.x != 0.f) || (v.y != 0.f) || (v.z != 0.f) || (v.w != 0.f);
            if (__any(nz) && (threadIdx.x & 63) == 0) atomicOr(flag, 1);
        }
        return;
    }
    const float* src; f16* dst; int n4;
    switch (blockIdx.y) {
        case 0:  src = X;  dst = Xh;  n4 = 786432;  break;
        case 1:  src = W1; dst = W1h; n4 = 442368;  break;
        default: src = W2; dst = W2h; n4 = 147456;  break;
    }
    if (tid < n4) {
        float4 v = ((const float4*)src)[tid];
        f16x4 o = {(f16)v.x, (f16)v.y, (f16)v.z, (f16)v.w};
        ((f16x4*)dst)[tid] = o;
    }
}

// ---------------------------------------------------------------------------
// QKV GEMM, f16 inputs, reg-prefetched staging. 128x128 tile, 4 waves 2x2,
// BK=32. Epilogue: bias, l2-norm Q/K rows, fold exp(min(ls,MAX))*LOG2E into Q.
// ---------------------------------------------------------------------------
__global__ __launch_bounds__(256, 3) void qkv_gemm(const f16* __restrict__ Xh,
                                                   const f16* __restrict__ Wh,
                                                   const float* __restrict__ bias,
                                                   const float* __restrict__ logit_scale,
                                                   f16* __restrict__ qkv16)
{
    __shared__ f16 As[128 * GP];
    __shared__ f16 Bs[128 * GP];
    const int t    = threadIdx.x;
    const int w    = t >> 6;
    const int lane = t & 63;
    const int quad = lane >> 4;
    const int sub  = lane & 15;
    const int wm   = w & 1, wn = w >> 1;
    const int f0   = blockIdx.x * 128;
    const int m0   = blockIdx.y * 128;
    const int srow = t >> 1;
    const int sk   = (t & 1) * 16;

    const f16* ag = Xh + (size_t)(m0 + srow) * CH + sk;
    const f16* bg = Wh + (size_t)(f0 + srow) * CH + sk;
    f16x8 a0 = *(const f16x8*)(ag);
    f16x8 a1 = *(const f16x8*)(ag + 8);
    f16x8 b0 = *(const f16x8*)(bg);
    f16x8 b1 = *(const f16x8*)(bg + 8);

    f32x4 acc[4][4];
#pragma unroll
    for (int i = 0; i < 4; ++i)
#pragma unroll
        for (int j = 0; j < 4; ++j) acc[i][j] = (f32x4){0.f, 0.f, 0.f, 0.f};

    for (int k0 = 0; k0 < CH; k0 += 32) {
        __syncthreads();
        *(f16x8*)&As[srow * GP + sk + 0] = a0;
        *(f16x8*)&As[srow * GP + sk + 8] = a1;
        *(f16x8*)&Bs[srow * GP + sk + 0] = b0;
        *(f16x8*)&Bs[srow * GP + sk + 8] = b1;
        __syncthreads();
        if (k0 + 32 < CH) {
            a0 = *(const f16x8*)(ag + k0 + 32);
            a1 = *(const f16x8*)(ag + k0 + 40);
            b0 = *(const f16x8*)(bg + k0 + 32);
            b1 = *(const f16x8*)(bg + k0 + 40);
        }
        f16x8 af[4], bf[4];
#pragma unroll
        for (int i = 0; i < 4; ++i) {
            af[i] = *(const f16x8*)&As[(wm * 64 + i * 16 + sub) * GP + quad * 8];
            bf[i] = *(const f16x8*)&Bs[(wn * 64 + i * 16 + sub) * GP + quad * 8];
        }
#pragma unroll
        for (int i = 0; i < 4; ++i)
#pragma unroll
            for (int j = 0; j < 4; ++j)
                acc[i][j] = __builtin_amdgcn_mfma_f32_16x16x32_f16(af[i], bf[j], acc[i][j], 0, 0, 0);
    }

    const int t3 = f0 / CH;
    const int h  = ((f0 + wn * 64) % CH) >> 6;
    f16* dst = qkv16 + (size_t)t3 * QSZ;
    float lsv = (t3 == 0) ? __expf(fminf(logit_scale[h], LSMAX)) * LOG2E : 1.0f;
    float bb[4];
#pragma unroll
    for (int j = 0; j < 4; ++j) bb[j] = bias[f0 + wn * 64 + j * 16 + sub];
#pragma unroll
    for (int i = 0; i < 4; ++i) {
#pragma unroll
        for (int r = 0; r < 4; ++r) {
            int m = m0 + wm * 64 + i * 16 + quad * 4 + r;
            int n = m >> 11, l = m & 2047;
            float v[4];
#pragma unroll
            for (int j = 0; j < 4; ++j) v[j] = acc[i][j][r] + bb[j];
            float scale = 1.0f;
            if (t3 < 2) {
                float ss = v[0] * v[0] + v[1] * v[1] + v[2] * v[2] + v[3] * v[3];
#pragma unroll
                for (int mk = 1; mk < 16; mk <<= 1) ss += __shfl_xor(ss, mk, 64);
                scale = 1.0f / fmaxf(sqrtf(ss), 1e-12f);
                if (t3 == 0) scale *= lsv;
            }
            f16* drow = dst + (((size_t)n * NH + h) * SEQ + l) * HD;
#pragma unroll
            for (int j = 0; j < 4; ++j)
                drow[j * 16 + sub] = (f16)(v[j] * scale);
        }
    }
}

// ---------------------------------------------------------------------------
// Flash attention, f16 MFMA, KC=128. Q and K fragments are loaded DIRECTLY
// from global (B-frag pattern is cacheline-dense; K is L2-hot; all 4 waves
// share the same K-frags so LDS staging was pure overhead). Only V (needs
// transpose) and P (needs layout swap) go through LDS. V double-buffered:
// ONE barrier per iteration. Log2-domain softmax, l via ones-MFMA.
// ---------------------------------------------------------------------------
__global__ __launch_bounds__(256, 3) void attn(const f16* __restrict__ Qh,
                                               const f16* __restrict__ Kh,
                                               const f16* __restrict__ Vh,
                                               const float* __restrict__ M32,
                                               const float* __restrict__ lscale,
                                               const int* __restrict__ flag,
                                               f16* __restrict__ Og)
{
    __shared__ f16 Vt[2][64 * VP];  // [d][key 0..127] x2   34.8 KB
    __shared__ f16 Ps[64 * PPIT];   // P tile                9.7 KB

    const int t    = threadIdx.x;
    const int w    = t >> 6;
    const int lane = t & 63;
    const int quad = lane >> 4;
    const int sub  = lane & 15;
    const int qb   = blockIdx.x * 64;
    const int h    = blockIdx.y, n = blockIdx.z;
    const bool has_mask = (*flag) != 0;

    const f16* Qg = Qh + ((size_t)(n * NH + h) * SEQ + qb) * HD;
    const f16* Kg = Kh + (size_t)(n * NH + h) * SEQ * HD;
    const f16* Vg = Vh + (size_t)(n * NH + h) * SEQ * HD;
    const float* Mg = M32 + (size_t)(qb + w * 16 + quad * 4) * SEQ;

    // Q fragments direct from global (A-layout: m=sub row, k=quad*8..)
    f16x8 qf0 = *(const f16x8*)&Qg[(w * 16 + sub) * 64 + quad * 8];
    f16x8 qf1 = *(const f16x8*)&Qg[(w * 16 + sub) * 64 + 32 + quad * 8];

    // V chunk 0 -> regs -> buf0; prefetch chunk 1 into regs
    f16x8 vr0, vr1, vr2, vr3;
    {
        const f16* vp = Vg + (2 * lane) * 64 + w * 16;
        vr0 = *(const f16x8*)(vp + 0);
        vr1 = *(const f16x8*)(vp + 8);
        vr2 = *(const f16x8*)(vp + 64);
        vr3 = *(const f16x8*)(vp + 72);
    }
#pragma unroll
    for (int j = 0; j < 8; ++j) {
        *(f16x2*)&Vt[0][(w * 16 + j) * VP + 2 * lane]     = (f16x2){vr0[j], vr2[j]};
        *(f16x2*)&Vt[0][(w * 16 + 8 + j) * VP + 2 * lane] = (f16x2){vr1[j], vr3[j]};
    }
    {
        const f16* vp = Vg + (128 + 2 * lane) * 64 + w * 16;
        vr0 = *(const f16x8*)(vp + 0);
        vr1 = *(const f16x8*)(vp + 8);
        vr2 = *(const f16x8*)(vp + 64);
        vr3 = *(const f16x8*)(vp + 72);
    }
    __syncthreads();   // buf0 visible

    const f16x8 ones = {(f16)1.f, (f16)1.f, (f16)1.f, (f16)1.f,
                        (f16)1.f, (f16)1.f, (f16)1.f, (f16)1.f};
    f32x4 o[4];
    f32x4 l_acc = (f32x4){0.f, 0.f, 0.f, 0.f};
    float m_run[4];
#pragma unroll
    for (int dt = 0; dt < 4; ++dt) o[dt] = (f32x4){0.f, 0.f, 0.f, 0.f};
#pragma unroll
    for (int r = 0; r < 4; ++r) m_run[r] = -1e30f;

    const int NITER = SEQ / 128;
    for (int c = 0; c < NITER; ++c) {
        const int c0 = c * 128;
        const int cur = c & 1, nxt = cur ^ 1;
        if (c > 0) __syncthreads();   // prev iter's readers of buf[nxt] done

        // issue K-frag loads (half 0) early; V-restage DS ops fill latency
        const f16* kbase = Kg + (size_t)c0 * 64;
        f16x8 kf[8];
#pragma unroll
        for (int ct = 0; ct < 8; ++ct)
            kf[ct] = *(const f16x8*)&kbase[(ct * 16 + sub) * 64 + quad * 8];

        if (c + 1 < NITER) {   // store prefetched chunk c+1 into buf[nxt]
#pragma unroll
            for (int j = 0; j < 8; ++j) {
                *(f16x2*)&Vt[nxt][(w * 16 + j) * VP + 2 * lane]     = (f16x2){vr0[j], vr2[j]};
                *(f16x2*)&Vt[nxt][(w * 16 + 8 + j) * VP + 2 * lane] = (f16x2){vr1[j], vr3[j]};
            }
            if (c + 2 < NITER) {   // prefetch chunk c+2
                const f16* vp = Vg + ((c + 2) * 128 + 2 * lane) * 64 + w * 16;
                vr0 = *(const f16x8*)(vp + 0);
                vr1 = *(const f16x8*)(vp + 8);
                vr2 = *(const f16x8*)(vp + 64);
                vr3 = *(const f16x8*)(vp + 72);
            }
        }

        // S = Q.K^T over 128 keys, K-frags direct from global (two k-halves)
        f32x4 s[8];
#pragma unroll
        for (int ct = 0; ct < 8; ++ct) {
            f32x4 a = (f32x4){0.f, 0.f, 0.f, 0.f};
            s[ct] = __builtin_amdgcn_mfma_f32_16x16x32_f16(qf0, kf[ct], a, 0, 0, 0);
        }
#pragma unroll
        for (int ct = 0; ct < 8; ++ct)
            kf[ct] = *(const f16x8*)&kbase[(ct * 16 + sub) * 64 + 32 + quad * 8];
#pragma unroll
        for (int ct = 0; ct < 8; ++ct)
            s[ct] = __builtin_amdgcn_mfma_f32_16x16x32_f16(qf1, kf[ct], s[ct], 0, 0, 0);

        if (has_mask) {   // rare path: fp32 mask direct, scaled to log2 domain
#pragma unroll
            for (int ct = 0; ct < 8; ++ct)
#pragma unroll
                for (int r = 0; r < 4; ++r)
                    s[ct][r] += LOG2E * Mg[(size_t)r * SEQ + c0 + ct * 16 + sub];
        }
        // row max over 128 cols + running, packed-f16 16-lane butterfly
        float mnew[4];
#pragma unroll
        for (int r = 0; r < 4; ++r) {
            float a01 = fmaxf(s[0][r], s[1][r]), a23 = fmaxf(s[2][r], s[3][r]);
            float a45 = fmaxf(s[4][r], s[5][r]), a67 = fmaxf(s[6][r], s[7][r]);
            mnew[r] = fmaxf(fmaxf(fmaxf(a01, a23), fmaxf(a45, a67)), m_run[r]);
        }
        {
            union { f16x2 h; int i; } p0, p1, v0, v1;
            p0.h = (f16x2){(f16)mnew[0], (f16)mnew[1]};
            p1.h = (f16x2){(f16)mnew[2], (f16)mnew[3]};
#pragma unroll
            for (int mk = 1; mk < 16; mk <<= 1) {
                v0.i = __shfl_xor(p0.i, mk, 64);
                v1.i = __shfl_xor(p1.i, mk, 64);
                p0.h = __builtin_elementwise_max(p0.h, v0.h);
                p1.h = __builtin_elementwise_max(p1.h, v1.h);
            }
            mnew[0] = (float)p0.h[0]; mnew[1] = (float)p0.h[1];
            mnew[2] = (float)p1.h[0]; mnew[3] = (float)p1.h[1];
        }
        float alpha[4];
#pragma unroll
        for (int r = 0; r < 4; ++r) {
            alpha[r] = exp2f(m_run[r] - mnew[r]);
            m_run[r] = mnew[r];
        }
        // rescale O and l
#pragma unroll
        for (int dt = 0; dt < 4; ++dt)
#pragma unroll
            for (int r = 0; r < 4; ++r) o[dt][r] *= alpha[r];
#pragma unroll
        for (int r = 0; r < 4; ++r) l_acc[r] *= alpha[r];

        // two 64-key halves through the shared P tile (wave-private rows)
#pragma unroll
        for (int hf = 0; hf < 2; ++hf) {
#pragma unroll
            for (int ct = 0; ct < 4; ++ct)
#pragma unroll
                for (int r = 0; r < 4; ++r) {
                    float p = exp2f(s[hf * 4 + ct][r] - mnew[r]);
                    Ps[(w * 16 + quad * 4 + r) * PPIT + ct * 16 + sub] = (f16)p;
                }
            f16x4 p00 = *(const f16x4*)&Ps[(w * 16 + sub) * PPIT + quad * 8];
            f16x4 p01 = *(const f16x4*)&Ps[(w * 16 + sub) * PPIT + quad * 8 + 4];
            f16x4 p10 = *(const f16x4*)&Ps[(w * 16 + sub) * PPIT + 32 + quad * 8];
            f16x4 p11 = *(const f16x4*)&Ps[(w * 16 + sub) * PPIT + 32 + quad * 8 + 4];
            f16x8 pf0 = {p00[0], p00[1], p00[2], p00[3], p01[0], p01[1], p01[2], p01[3]};
            f16x8 pf1 = {p10[0], p10[1], p10[2], p10[3], p11[0], p11[1], p11[2], p11[3]};
            l_acc = __builtin_amdgcn_mfma_f32_16x16x32_f16(pf0, ones, l_acc, 0, 0, 0);
            l_acc = __builtin_amdgcn_mfma_f32_16x16x32_f16(pf1, ones, l_acc, 0, 0, 0);
#pragma unroll
            for (int dt = 0; dt < 4; ++dt) {
                f16x8 vf0 = *(const f16x8*)&Vt[cur][(dt * 16 + sub) * VP + hf * 64 + quad * 8];
                f16x8 vf1 = *(const f16x8*)&Vt[cur][(dt * 16 + sub) * VP + hf * 64 + 32 + quad * 8];
                o[dt] = __builtin_amdgcn_mfma_f32_16x16x32_f16(pf0, vf0, o[dt], 0, 0, 0);
                o[dt] = __builtin_amdgcn_mfma_f32_16x16x32_f16(pf1, vf1, o[dt], 0, 0, 0);
            }
        }
    }
    // epilogue
    float lsc = lscale[h];
#pragma unroll
    for (int r = 0; r < 4; ++r) {
        float inv = lsc / l_acc[r];
        int q = qb + w * 16 + quad * 4 + r;
#pragma unroll
        for (int dt = 0; dt < 4; ++dt)
            Og[((size_t)n * SEQ + q) * CH + h * 64 + dt * 16 + sub] =
                (f16)(o[dt][r] * inv);
    }
}

// ---------------------------------------------------------------------------
// Output projection, f16 inputs, reg-prefetched staging. fp32 out.
// ---------------------------------------------------------------------------
__global__ __launch_bounds__(256, 3) void out_gemm(const f16* __restrict__ A,
                                                   const f16* __restrict__ Wh,
                                                   const float* __restrict__ bias,
                                                   float* __restrict__ out)
{
    __shared__ f16 As[128 * GP];
    __shared__ f16 Bs[128 * GP];
    const int t    = threadIdx.x;
    const int w    = t >> 6;
    const int lane = t & 63;
    const int quad = lane >> 4;
    const int sub  = lane & 15;
    const int wm   = w & 1, wn = w >> 1;
    const int f0   = blockIdx.x * 128;
    const int m0   = blockIdx.y * 128;
    const int srow = t >> 1;
    const int sk   = (t & 1) * 16;

    const f16* ag = A + (size_t)(m0 + srow) * CH + sk;
    const f16* bg = Wh + (size_t)(f0 + srow) * CH + sk;
    f16x8 a0 = *(const f16x8*)(ag);
    f16x8 a1 = *(const f16x8*)(ag + 8);
    f16x8 b0 = *(const f16x8*)(bg);
    f16x8 b1 = *(const f16x8*)(bg + 8);

    f32x4 acc[4][4];
#pragma unroll
    for (int i = 0; i < 4; ++i)
#pragma unroll
        for (int j = 0; j < 4; ++j) acc[i][j] = (f32x4){0.f, 0.f, 0.f, 0.f};

    for (int k0 = 0; k0 < CH; k0 += 32) {
        __syncthreads();
        *(f16x8*)&As[srow * GP + sk + 0] = a0;
        *(f16x8*)&As[srow * GP + sk + 8] = a1;
        *(f16x8*)&Bs[srow * GP + sk + 0] = b0;
        *(f16x8*)&Bs[srow * GP + sk + 8] = b1;
        __syncthreads();
        if (k0 + 32 < CH) {
            a0 = *(const f16x8*)(ag + k0 + 32);
            a1 = *(const f16x8*)(ag + k0 + 40);
            b0 = *(const f16x8*)(bg + k0 + 32);
            b1 = *(const f16x8*)(bg + k0 + 40);
        }
        f16x8 af[4], bf[4];
#pragma unroll
        for (int i = 0; i < 4; ++i) {
            af[i] = *(const f16x8*)&As[(wm * 64 + i * 16 + sub) * GP + quad * 8];
            bf[i] = *(const f16x8*)&Bs[(wn * 64 + i * 16 + sub) * GP + quad * 8];
        }
#pragma unroll
        for (int i = 0; i < 4; ++i)
#pragma unroll
            for (int j = 0; j < 4; ++j)
                acc[i][j] = __builtin_amdgcn_mfma_f32_16x16x32_f16(af[i], bf[j], acc[i][j], 0, 0, 0);
    }
    float bb[4];
#pragma unroll
    for (int j = 0; j < 4; ++j) bb[j] = bias[f0 + wn * 64 + j * 16 + sub];
#pragma unroll
    for (int i = 0; i < 4; ++i)
#pragma unroll
        for (int r = 0; r < 4; ++r) {
            int m = m0 + wm * 64 + i * 16 + quad * 4 + r;
            float* orow = out + (size_t)m * CH + f0 + wn * 64;
#pragma unroll
            for (int j = 0; j < 4; ++j)
                orow[j * 16 + sub] = acc[i][j][r] + bb[j];
        }
}

extern "C" void kernel_launch(void* const* d_in, const int* in_sizes, int n_in,
                              void* d_out, int out_size, void* d_ws, size_t ws_size,
                              hipStream_t stream) {
    const float* x    = (const float*)d_in[0];
    const float* w1   = (const float*)d_in[1];
    const float* b1   = (const float*)d_in[2];
    const float* ls   = (const float*)d_in[3];
    const float* lrn  = (const float*)d_in[4];
    const float* w2   = (const float*)d_in[5];
    const float* b2   = (const float*)d_in[6];
    const float* msk  = (const float*)d_in[7];
    f16*   ws16 = (f16*)d_ws;
    int*   flag = (int*)(ws16 + FLAGO);
    float* out  = (float*)d_out;

    (void)hipMemsetAsync(flag, 0, 4, stream);
    hipLaunchKernelGGL(cvt_f16, dim3(4096, 4), dim3(256), 0, stream,
                       x, w1, w2, msk,
                       ws16 + XHOFF, ws16 + W1OFF, ws16 + W2OFF, flag);
    hipLaunchKernelGGL(qkv_gemm, dim3(F3 / 128, (NB * SEQ) / 128), dim3(256), 0, stream,
                       ws16 + XHOFF, ws16 + W1OFF, b1, ls, ws16);
    hipLaunchKernelGGL(attn, dim3(SEQ / 64, NH, NB), dim3(256), 0, stream,
                       ws16, ws16 + QSZ, ws16 + 2 * QSZ, msk, lrn, flag,
                       ws16 + OATT);
    hipLaunchKernelGGL(out_gemm, dim3(CH / 128, (NB * SEQ) / 128), dim3(256), 0, stream,
                       ws16 + OATT, ws16 + W2OFF, b2, out);
}